// Round 1
// baseline (71.500 us; speedup 1.0000x reference)
//
#include <hip/hip_runtime.h>

// Fused: roll(+1 over H) -> 3-tap H-conv (128ch -> 8 = [k4=4][o2=2]) with w1
//        -> 3-tap W-conv (8 -> 128 = [i32=32][k4=4]) with w2
// x  : (128, 56, 56) f32
// w1 : (4, 64, 3)    f32   w1[k][i][j]
// w2 : (32, 2, 3)    f32   w2[i32][o2][t]
// out: (128, 56, 56) f32   channel c = i32*4 + k4

#define HH 56
#define WW 56

__global__ __launch_bounds__(256) void fused_shift_conv(
    const float* __restrict__ x,
    const float* __restrict__ w1,
    const float* __restrict__ w2,
    float* __restrict__ out)
{
    __shared__ float w1s[64 * 12];        // [i][j][k] reordered for k-unrolled reads
    __shared__ float w2s[192];            // [i32][o2][t] as-is
    __shared__ float t4s[2][4][WW + 2];   // [o2][k4][n+1], zero pad at both ends

    const int tid = threadIdx.x;
    const int m = blockIdx.x;             // output row

    // ---- stage weights into LDS ----
    for (int idx = tid; idx < 768; idx += 256) {
        int k = idx / 192;
        int r = idx - k * 192;
        int i = r / 3;
        int j = r - i * 3;
        w1s[i * 12 + j * 4 + k] = w1[idx];
    }
    if (tid < 192) w2s[tid] = w2[tid];
    if (tid < 16) {
        int o = tid >> 3;
        int k = (tid >> 1) & 3;
        int side = tid & 1;
        t4s[o][k][side * (WW + 1)] = 0.0f;
    }
    __syncthreads();

    // ---- stage 1: t4[k4][o2][n] for this row m ----
    // thread (n, o): n = tid % 56, o = tid / 56, tid < 112
    if (tid < 112) {
        const int n = tid % 56;
        const int o = tid / 56;
        float acc0 = 0.f, acc1 = 0.f, acc2 = 0.f, acc3 = 0.f;
        #pragma unroll
        for (int j = 0; j < 3; ++j) {
            const int h_t = m + j - 1;                 // unfold tap row (zero-padded)
            if (h_t >= 0 && h_t < HH) {
                int h_src = h_t - 1;                   // roll(+1): out[h] = in[h-1 mod 56]
                if (h_src < 0) h_src += HH;
                const float* xp = x + (size_t)h_src * WW + n + (size_t)o * (HH * WW);
                #pragma unroll 8
                for (int i = 0; i < 64; ++i) {
                    const float xv = xp[(size_t)i * 2 * (HH * WW)];
                    const float* wp = &w1s[i * 12 + j * 4];
                    acc0 += xv * wp[0];
                    acc1 += xv * wp[1];
                    acc2 += xv * wp[2];
                    acc3 += xv * wp[3];
                }
            }
        }
        t4s[o][0][n + 1] = acc0;
        t4s[o][1][n + 1] = acc1;
        t4s[o][2][n + 1] = acc2;
        t4s[o][3][n + 1] = acc3;
    }
    __syncthreads();

    // ---- stage 2: 128 channels x 56 cols for this row ----
    for (int item = tid; item < 128 * WW; item += 256) {
        const int cc = item / WW;
        const int n = item - cc * WW;
        const int i32 = cc >> 2;
        const int k4 = cc & 3;
        const float* wp = &w2s[i32 * 6];
        const float s = t4s[0][k4][n]     * wp[0]
                      + t4s[0][k4][n + 1] * wp[1]
                      + t4s[0][k4][n + 2] * wp[2]
                      + t4s[1][k4][n]     * wp[3]
                      + t4s[1][k4][n + 1] * wp[4]
                      + t4s[1][k4][n + 2] * wp[5];
        out[(size_t)cc * (HH * WW) + (size_t)m * WW + n] = s;
    }
}

extern "C" void kernel_launch(void* const* d_in, const int* in_sizes, int n_in,
                              void* d_out, int out_size, void* d_ws, size_t ws_size,
                              hipStream_t stream) {
    const float* x  = (const float*)d_in[0];
    const float* w1 = (const float*)d_in[1];
    const float* w2 = (const float*)d_in[2];
    float* out = (float*)d_out;
    fused_shift_conv<<<dim3(HH), dim3(256), 0, stream>>>(x, w1, w2, out);
}

// Round 2
// 60.270 us; speedup vs baseline: 1.1863x; 1.1863x over previous
//
#include <hip/hip_runtime.h>

// Fused: roll(+1 over H) -> 3-tap H-conv (128ch -> 8 = [k4=4][o2=2]) with w1
//        -> 3-tap W-conv (8 -> 128 = [i32=32][k4=4]) with w2
// x  : (128, 56, 56) f32
// w1 : (4, 64, 3)    f32   w1[k][i][j]
// w2 : (32, 2, 3)    f32   w2[i32][o2][t]
// out: (128, 56, 56) f32   channel c = i32*4 + k4
//
// Round-2 mapping: grid = (4 n-tiles, 56 rows) = 224 blocks, 512 threads.
// Stage-1 reduction over i=64 split across 16 chunks of 4 per thread
// (12 loads / 48 FMAs per thread instead of 192 loads on 112 threads),
// then LDS partial-reduce. 16 t4 columns per block cover the 14-column
// output tile + stage-2 halo.

#define HH 56
#define WW 56
#define HW (HH * WW)

__global__ __launch_bounds__(512) void fused_shift_conv2(
    const float* __restrict__ x,
    const float* __restrict__ w1,
    const float* __restrict__ w2,
    float* __restrict__ out)
{
    __shared__ float w1s[64 * 12];          // [i][j][k4]
    __shared__ float w2s[192];              // [i32][o2][t]
    __shared__ float part[16][2][16][4];    // [ic][o][nl][k] == flat tid*4+k
    __shared__ float t4s[2][4][16];         // [o][k][nl], nl holds global col n0+nl-1

    const int tid = threadIdx.x;
    const int m  = blockIdx.y;              // output row
    const int n0 = blockIdx.x * 14;         // output col tile base

    // ---- stage weights into LDS ----
    for (int idx = tid; idx < 768; idx += 512) {
        int k = idx / 192;
        int r = idx - k * 192;
        int i = r / 3;
        int j = r - i * 3;
        w1s[i * 12 + j * 4 + k] = w1[idx];
    }
    if (tid < 192) w2s[tid] = w2[tid];
    __syncthreads();

    // ---- stage 1: partial sums over i-chunk ----
    const int nl = tid & 15;                // 16 t4 columns (incl. halo)
    const int o  = (tid >> 4) & 1;
    const int ic = tid >> 5;                // 16 chunks of 4 channels
    const int n_g = n0 + nl - 1;            // global column of this t4 slot

    float a0 = 0.f, a1 = 0.f, a2 = 0.f, a3 = 0.f;
    if (n_g >= 0 && n_g < WW) {
        #pragma unroll
        for (int j = 0; j < 3; ++j) {
            const int h_t = m + j - 1;              // unfold tap row (zero-pad)
            if (h_t >= 0 && h_t < HH) {
                int h_src = h_t - 1;                // roll(+1): out[h]=in[h-1 mod 56]
                if (h_src < 0) h_src += HH;
                const float* xp = x + (size_t)(ic * 8 + o) * HW
                                    + (size_t)h_src * WW + n_g;
                #pragma unroll
                for (int ii = 0; ii < 4; ++ii) {
                    const float xv = xp[(size_t)ii * 2 * HW];
                    const float* wp = &w1s[(ic * 4 + ii) * 12 + j * 4];
                    a0 += xv * wp[0];
                    a1 += xv * wp[1];
                    a2 += xv * wp[2];
                    a3 += xv * wp[3];
                }
            }
        }
    }
    ((float4*)part)[tid] = make_float4(a0, a1, a2, a3);
    __syncthreads();

    // ---- reduce partials over ic: 2*16*4 = 128 outputs ----
    if (tid < 128) {
        const int k  = tid & 3;
        const int n  = (tid >> 2) & 15;
        const int oo = tid >> 6;
        float s = 0.f;
        #pragma unroll
        for (int c = 0; c < 16; ++c)
            s += part[c][oo][n][k];
        t4s[oo][k][n] = s;
    }
    __syncthreads();

    // ---- stage 2: 128 channels x 14 cols ----
    for (int item = tid; item < 128 * 14; item += 512) {
        const int cc = item / 14;
        const int nn = item - cc * 14;
        const int i32 = cc >> 2;
        const int k4 = cc & 3;
        const float* wp = &w2s[i32 * 6];
        // output col n0+nn reads t4 global cols n0+nn-1..+1 -> local nn..nn+2
        const float s = t4s[0][k4][nn]     * wp[0]
                      + t4s[0][k4][nn + 1] * wp[1]
                      + t4s[0][k4][nn + 2] * wp[2]
                      + t4s[1][k4][nn]     * wp[3]
                      + t4s[1][k4][nn + 1] * wp[4]
                      + t4s[1][k4][nn + 2] * wp[5];
        out[(size_t)cc * HW + (size_t)m * WW + (n0 + nn)] = s;
    }
}

extern "C" void kernel_launch(void* const* d_in, const int* in_sizes, int n_in,
                              void* d_out, int out_size, void* d_ws, size_t ws_size,
                              hipStream_t stream) {
    const float* x  = (const float*)d_in[0];
    const float* w1 = (const float*)d_in[1];
    const float* w2 = (const float*)d_in[2];
    float* out = (float*)d_out;
    fused_shift_conv2<<<dim3(4, 56), dim3(512), 0, stream>>>(x, w1, w2, out);
}

// Round 3
// 59.591 us; speedup vs baseline: 1.1998x; 1.0114x over previous
//
#include <hip/hip_runtime.h>

// Fused: roll(+1 over H) -> 3-tap H-conv (128ch -> 8 = [k4=4][o2=2]) with w1
//        -> 3-tap W-conv (8 -> 128 = [i32=32][k4=4]) with w2
// x  : (128, 56, 56) f32
// w1 : (4, 64, 3)    f32   w1[k][i][j]
// w2 : (32, 2, 3)    f32   w2[i32][o2][t]
// out: (128, 56, 56) f32   channel c = i32*4 + k4
//
// Round-3: same (4 x 56) x 512 mapping as round 2, but all 12 x-loads are
// hoisted to the top as unconditional clamped-address loads (zeroed later
// with cndmask) so they overlap the w1/w2 LDS staging latency instead of
// serializing behind the weight barrier.

#define HH 56
#define WW 56
#define HW (HH * WW)

__global__ __launch_bounds__(512) void fused_shift_conv3(
    const float* __restrict__ x,
    const float* __restrict__ w1,
    const float* __restrict__ w2,
    float* __restrict__ out)
{
    __shared__ float w1s[64 * 12];          // [i][j][k4]
    __shared__ float w2s[192];              // [i32][o2][t]
    __shared__ float part[16][2][16][4];    // [ic][o][nl][k] == flat tid*4+k
    __shared__ float t4s[2][4][16];         // [o][k][nl]

    const int tid = threadIdx.x;
    const int m  = blockIdx.y;              // output row
    const int n0 = blockIdx.x * 14;         // output col tile base

    const int nl = tid & 15;                // 16 t4 columns (incl. halo)
    const int o  = (tid >> 4) & 1;
    const int ic = tid >> 5;                // 16 chunks of 4 channels
    const int n_g = n0 + nl - 1;            // global column of this t4 slot

    // ---- issue all 12 x loads FIRST (clamped, unconditional) ----
    const bool okn = (n_g >= 0 && n_g < WW);
    const int ngc = n_g < 0 ? 0 : (n_g > WW - 1 ? WW - 1 : n_g);
    float xr[3][4];
    bool okj[3];
    #pragma unroll
    for (int j = 0; j < 3; ++j) {
        const int h_t = m + j - 1;                  // unfold tap row (zero-pad)
        const bool okh = (h_t >= 0 && h_t < HH);
        okj[j] = okh && okn;
        int h_src = h_t - 1;                        // roll(+1): out[h]=in[h-1 mod 56]
        if (h_src < 0) h_src += HH;
        if (!okh) h_src = 0;                        // clamp (value discarded)
        const float* xp = x + (size_t)(ic * 8 + o) * HW + (size_t)h_src * WW + ngc;
        #pragma unroll
        for (int ii = 0; ii < 4; ++ii)
            xr[j][ii] = xp[(size_t)ii * 2 * HW];    // channel = ic*8 + 2*ii + o
    }

    // ---- stage weights into LDS (overlaps the x loads above) ----
    for (int idx = tid; idx < 768; idx += 512) {
        int k = idx / 192;
        int r = idx - k * 192;
        int i = r / 3;
        int j = r - i * 3;
        w1s[i * 12 + j * 4 + k] = w1[idx];
    }
    if (tid < 192) w2s[tid] = w2[tid];
    __syncthreads();

    // ---- zero invalid taps, then stage-1 partial FMAs ----
    float a0 = 0.f, a1 = 0.f, a2 = 0.f, a3 = 0.f;
    #pragma unroll
    for (int j = 0; j < 3; ++j) {
        #pragma unroll
        for (int ii = 0; ii < 4; ++ii) {
            const float xv = okj[j] ? xr[j][ii] : 0.0f;
            const float* wp = &w1s[(ic * 4 + ii) * 12 + j * 4];
            a0 += xv * wp[0];
            a1 += xv * wp[1];
            a2 += xv * wp[2];
            a3 += xv * wp[3];
        }
    }
    ((float4*)part)[tid] = make_float4(a0, a1, a2, a3);
    __syncthreads();

    // ---- reduce partials over ic: 2*16*4 = 128 outputs ----
    if (tid < 128) {
        const int k  = tid & 3;
        const int n  = (tid >> 2) & 15;
        const int oo = tid >> 6;
        float s = 0.f;
        #pragma unroll
        for (int c = 0; c < 16; ++c)
            s += part[c][oo][n][k];
        t4s[oo][k][n] = s;
    }
    __syncthreads();

    // ---- stage 2: 128 channels x 14 cols ----
    for (int item = tid; item < 128 * 14; item += 512) {
        const int cc = item / 14;
        const int nn = item - cc * 14;
        const int i32 = cc >> 2;
        const int k4 = cc & 3;
        const float* wp = &w2s[i32 * 6];
        const float s = t4s[0][k4][nn]     * wp[0]
                      + t4s[0][k4][nn + 1] * wp[1]
                      + t4s[0][k4][nn + 2] * wp[2]
                      + t4s[1][k4][nn]     * wp[3]
                      + t4s[1][k4][nn + 1] * wp[4]
                      + t4s[1][k4][nn + 2] * wp[5];
        out[(size_t)cc * HW + (size_t)m * WW + (n0 + nn)] = s;
    }
}

extern "C" void kernel_launch(void* const* d_in, const int* in_sizes, int n_in,
                              void* d_out, int out_size, void* d_ws, size_t ws_size,
                              hipStream_t stream) {
    const float* x  = (const float*)d_in[0];
    const float* w1 = (const float*)d_in[1];
    const float* w2 = (const float*)d_in[2];
    float* out = (float*)d_out;
    fused_shift_conv3<<<dim3(4, 56), dim3(512), 0, stream>>>(x, w1, w2, out);
}